// Round 2
// baseline (629.017 us; speedup 1.0000x reference)
//
#include <hip/hip_runtime.h>

#define BB 4
#define CIN 256
#define HW 35200            // 200*176
#define AA 6
#define NANCH (AA * HW)     // 211200
#define TOPK 100
#define HSHIFT 17           // bin = float_bits >> 17 (15-bit key, monotone for s>=0)
#define NBIN 16384          // max bin for s<=1.0f is 0x3F800000>>17 = 8128
#define CAP 4096            // candidates per batch
#define SMAX 4096           // bitonic sort max size

// ---- shared head compute: 24 cls channels for 2 consecutive positions ----
__device__ __forceinline__ void head24(
    const float* __restrict__ x, const float* __restrict__ cls_w,
    const float* __restrict__ cls_b, unsigned b, unsigned hw,
    float acc[24][2]) {
  const float* xb = x + (size_t)b * CIN * HW + hw;
#pragma unroll
  for (int o = 0; o < 24; ++o) {
    float bv = cls_b[o];
    acc[o][0] = bv; acc[o][1] = bv;
  }
  for (int c = 0; c < CIN; ++c) {
    const float2 xv = *(const float2*)(xb + (size_t)c * HW);
#pragma unroll
    for (int o = 0; o < 24; ++o) {
      float w = cls_w[o * CIN + c];   // thread-uniform -> scalar load
      acc[o][0] = fmaf(xv.x, w, acc[o][0]);
      acc[o][1] = fmaf(xv.y, w, acc[o][1]);
    }
  }
}

__device__ __forceinline__ float maxfg_score(const float acc[24][2], int p, int a) {
  float l0 = acc[a * 4 + 0][p], l1 = acc[a * 4 + 1][p];
  float l2 = acc[a * 4 + 2][p], l3 = acc[a * 4 + 3][p];
  float m = fmaxf(fmaxf(l0, l1), fmaxf(l2, l3));
  float e0 = expf(l0 - m), e1 = expf(l1 - m);
  float e2 = expf(l2 - m), e3 = expf(l3 - m);
  float s = e0 + e1 + e2 + e3;
  return fmaxf(fmaxf(e1, e2), e3) / s;
}

// ---------------- K1: scores -> histogram ----------------
__global__ __launch_bounds__(256) void k1_hist(
    const float* __restrict__ x, const float* __restrict__ cls_w,
    const float* __restrict__ cls_b, unsigned int* __restrict__ hist) {
  unsigned g = (blockIdx.x * 256u + threadIdx.x) * 2u;   // [0, B*HW), even
  unsigned b = g / HW, hw = g % HW;                      // HW even -> no straddle
  float acc[24][2];
  head24(x, cls_w, cls_b, b, hw, acc);
#pragma unroll
  for (int p = 0; p < 2; ++p) {
#pragma unroll
    for (int a = 0; a < AA; ++a) {
      float mf = maxfg_score(acc, p, a);
      unsigned bin = __float_as_uint(mf) >> HSHIFT;
      atomicAdd(&hist[b * NBIN + bin], 1u);
    }
  }
}

// ---------------- K2: threshold bin per batch (parallel scan) ----------------
__global__ __launch_bounds__(256) void k2_thresh(
    const unsigned int* __restrict__ hist, unsigned int* __restrict__ thresh) {
  int b = blockIdx.x, tid = threadIdx.x;
  const unsigned* h = hist + (size_t)b * NBIN;
  unsigned r[64];
  unsigned base = tid * 64u;
  unsigned s = 0;
#pragma unroll
  for (int i = 0; i < 64; ++i) { r[i] = h[base + i]; s += r[i]; }
  __shared__ unsigned seg[256];
  seg[tid] = s;
  __syncthreads();
  // inclusive suffix scan (Hillis-Steele)
  for (int d = 1; d < 256; d <<= 1) {
    unsigned add = (tid + d < 256) ? seg[tid + d] : 0u;
    __syncthreads();
    seg[tid] += add;
    __syncthreads();
  }
  unsigned above = (tid < 255) ? seg[tid + 1] : 0u;
  if (above < TOPK && above + s >= TOPK) {   // exactly one thread
    unsigned c = above, T = 0;
    for (int i = 63; i >= 0; --i) {
      c += r[i];
      if (c >= TOPK) { T = base + (unsigned)i; break; }
    }
    thresh[b] = (T > 0) ? T - 1 : 0;   // 1-bin insurance margin
  }
}

// ---------------- K3: recompute scores, compact candidates ----------------
__global__ __launch_bounds__(256) void k3_compact(
    const float* __restrict__ x, const float* __restrict__ cls_w,
    const float* __restrict__ cls_b, const unsigned int* __restrict__ thresh,
    unsigned int* __restrict__ cand_count, unsigned long long* __restrict__ cand) {
  unsigned g = (blockIdx.x * 256u + threadIdx.x) * 2u;
  unsigned b = g / HW, hw = g % HW;
  float acc[24][2];
  head24(x, cls_w, cls_b, b, hw, acc);   // bit-identical to k1
  unsigned T = thresh[b];
#pragma unroll
  for (int p = 0; p < 2; ++p) {
#pragma unroll
    for (int a = 0; a < AA; ++a) {
      float mf = maxfg_score(acc, p, a);
      unsigned bits = __float_as_uint(mf);
      if ((bits >> HSHIFT) >= T) {
        unsigned pos = atomicAdd(&cand_count[b], 1u);
        if (pos < CAP) {
          unsigned n = (hw + p) * AA + a;
          cand[(size_t)b * CAP + pos] =
              ((unsigned long long)bits << 32) | (unsigned)(~n);
        }
      }
    }
  }
}

// ---------------- K4: bitonic sort (runtime size), emit topk ----------------
__global__ __launch_bounds__(256) void k4_sort(
    const unsigned long long* __restrict__ cand,
    const unsigned int* __restrict__ cand_count, unsigned int* __restrict__ topk) {
  int b = blockIdx.x, tid = threadIdx.x;
  __shared__ unsigned long long sh[SMAX];
  unsigned cnt = cand_count[b];
  if (cnt > CAP) cnt = CAP;
  unsigned S = 128;
  while (S < cnt) S <<= 1;
  for (unsigned t = tid; t < S; t += 256)
    sh[t] = (t < cnt) ? cand[(size_t)b * CAP + t] : 0ULL;
  __syncthreads();
  for (unsigned kk = 2; kk <= S; kk <<= 1) {
    for (unsigned jj = kk >> 1; jj > 0; jj >>= 1) {
      for (unsigned t = tid; t < S; t += 256) {
        unsigned ixj = t ^ jj;
        if (ixj > t) {
          unsigned long long a = sh[t], c = sh[ixj];
          bool sw = ((t & kk) == 0) ? (a < c) : (a > c);  // descending
          if (sw) { sh[t] = c; sh[ixj] = a; }
        }
      }
      __syncthreads();
    }
  }
  if (tid < TOPK)
    topk[b * TOPK + tid] = ~(unsigned)(sh[tid] & 0xFFFFFFFFULL);
}

// ---------------- K5: final heads + decode for selected anchors ----------------
__global__ __launch_bounds__(256) void k5_out(
    const float* __restrict__ x, const float* __restrict__ cls_w,
    const float* __restrict__ cls_b, const float* __restrict__ reg_w,
    const float* __restrict__ reg_b, const float* __restrict__ anchors,
    const unsigned int* __restrict__ topk, float* __restrict__ out) {
  int bk = blockIdx.x;            // [0, B*TOPK)
  int b = bk / TOPK, k = bk % TOPK;
  unsigned n = topk[b * TOPK + k];
  int a = (int)(n % AA);
  unsigned hw = n / AA;
  int tid = threadIdx.x;          // 256 == CIN

  float xv = x[(size_t)b * CIN * HW + (size_t)tid * HW + hw];
  float part[11];
#pragma unroll
  for (int j = 0; j < 4; ++j) part[j] = xv * cls_w[(a * 4 + j) * CIN + tid];
#pragma unroll
  for (int j = 0; j < 7; ++j) part[4 + j] = xv * reg_w[(a * 7 + j) * CIN + tid];

#pragma unroll
  for (int j = 0; j < 11; ++j) {
    float v = part[j];
    for (int off = 32; off > 0; off >>= 1) v += __shfl_down(v, off, 64);
    part[j] = v;
  }
  __shared__ float red[4][11];
  int wave = tid >> 6, lane = tid & 63;
  if (lane == 0) {
#pragma unroll
    for (int j = 0; j < 11; ++j) red[wave][j] = part[j];
  }
  __syncthreads();
  if (tid == 0) {
    float tot[11];
#pragma unroll
    for (int j = 0; j < 11; ++j)
      tot[j] = red[0][j] + red[1][j] + red[2][j] + red[3][j];
    float l0 = tot[0] + cls_b[a * 4 + 0];
    float l1 = tot[1] + cls_b[a * 4 + 1];
    float l2 = tot[2] + cls_b[a * 4 + 2];
    float l3 = tot[3] + cls_b[a * 4 + 3];
    float m = fmaxf(fmaxf(l0, l1), fmaxf(l2, l3));
    float e0 = expf(l0 - m), e1 = expf(l1 - m);
    float e2 = expf(l2 - m), e3 = expf(l3 - m);
    float inv = 1.0f / (e0 + e1 + e2 + e3);
    float* os = out + ((size_t)b * TOPK + k) * 4;
    os[0] = e0 * inv; os[1] = e1 * inv; os[2] = e2 * inv; os[3] = e3 * inv;
    const float* an = anchors + (size_t)n * 7;
    float xa = an[0], ya = an[1], za = an[2];
    float dxa = an[3], dya = an[4], dza = an[5], ra = an[6];
    float xt = tot[4] + reg_b[a * 7 + 0];
    float yt = tot[5] + reg_b[a * 7 + 1];
    float zt = tot[6] + reg_b[a * 7 + 2];
    float dxt = tot[7] + reg_b[a * 7 + 3];
    float dyt = tot[8] + reg_b[a * 7 + 4];
    float dzt = tot[9] + reg_b[a * 7 + 5];
    float rt = tot[10] + reg_b[a * 7 + 6];
    float diag = sqrtf(dxa * dxa + dya * dya);
    float* ob = out + (size_t)BB * TOPK * 4 + ((size_t)b * TOPK + k) * 7;
    ob[0] = xt * diag + xa;
    ob[1] = yt * diag + ya;
    ob[2] = zt * dza + za;
    ob[3] = expf(dxt) * dxa;
    ob[4] = expf(dyt) * dya;
    ob[5] = expf(dzt) * dza;
    ob[6] = rt + ra;
  }
}

extern "C" void kernel_launch(void* const* d_in, const int* in_sizes, int n_in,
                              void* d_out, int out_size, void* d_ws, size_t ws_size,
                              hipStream_t stream) {
  const float* x       = (const float*)d_in[0];
  const float* cls_w   = (const float*)d_in[1];
  const float* cls_b   = (const float*)d_in[2];
  const float* reg_w   = (const float*)d_in[3];
  const float* reg_b   = (const float*)d_in[4];
  const float* anchors = (const float*)d_in[5];
  float* out = (float*)d_out;

  // workspace layout (total ~386 KB)
  char* ws = (char*)d_ws;
  size_t off = 0;
  unsigned int* hist = (unsigned int*)(ws + off);        off += (size_t)BB * NBIN * 4;  // 256 KB
  unsigned int* cand_count = (unsigned int*)(ws + off);  off += 64;
  unsigned int* thresh = (unsigned int*)(ws + off);      off += 64;
  unsigned long long* cand = (unsigned long long*)(ws + off); off += (size_t)BB * CAP * 8; // 128 KB
  unsigned int* topk = (unsigned int*)(ws + off);        off += ((size_t)BB * TOPK * 4 + 63) & ~(size_t)63;

  // zero histogram + candidate counters (contiguous)
  hipMemsetAsync(hist, 0, (size_t)BB * NBIN * 4 + 64, stream);

  const int GRID12 = (BB * HW) / 512;   // 275 blocks, 2 positions/thread
  k1_hist<<<GRID12, 256, 0, stream>>>(x, cls_w, cls_b, hist);
  k2_thresh<<<BB, 256, 0, stream>>>(hist, thresh);
  k3_compact<<<GRID12, 256, 0, stream>>>(x, cls_w, cls_b, thresh, cand_count, cand);
  k4_sort<<<BB, 256, 0, stream>>>(cand, cand_count, topk);
  k5_out<<<BB * TOPK, 256, 0, stream>>>(x, cls_w, cls_b, reg_w, reg_b, anchors,
                                        topk, out);
}

// Round 3
// 504.640 us; speedup vs baseline: 1.2465x; 1.2465x over previous
//
#include <hip/hip_runtime.h>

#define BB 4
#define CIN 256
#define HW 35200            // 200*176
#define AA 6
#define NANCH (AA * HW)     // 211200
#define TOPK 100
#define HSHIFT 17           // bin = float_bits >> 17 (monotone for s>=0)
#define NBIN 16384
#define CAP 8192            // candidates per batch
#define SMAX 8192           // bitonic sort max size (64KB LDS)

__device__ __forceinline__ float sc4(float4 l) {
  float m = fmaxf(fmaxf(l.x, l.y), fmaxf(l.z, l.w));
  float e0 = expf(l.x - m), e1 = expf(l.y - m);
  float e2 = expf(l.z - m), e3 = expf(l.w - m);
  return fmaxf(fmaxf(e1, e2), e3) / (e0 + e1 + e2 + e3);
}

// stage cls weights transposed into LDS: swf[c*24+o] = cls_w[o*CIN+c]
#define STAGE_W()                                                        \
  __shared__ __align__(16) float swf[CIN * 24];                          \
  for (int i = threadIdx.x; i < CIN * 24; i += 256) {                    \
    int o = i / CIN, c = i % CIN;                                        \
    swf[c * 24 + o] = cls_w[i];                                          \
  }                                                                      \
  __syncthreads();                                                       \
  const float4* sw4 = (const float4*)swf;

#define FMA_ROW(A, W) \
  A.x = fmaf(xv, W.x, A.x); A.y = fmaf(xv, W.y, A.y); \
  A.z = fmaf(xv, W.z, A.z); A.w = fmaf(xv, W.w, A.w);

// computes b, hw, and 6 anchor scores s0..s5 for position g = blk*256+tid
#define HEAD_BODY()                                                      \
  unsigned g = blockIdx.x * 256u + threadIdx.x;                          \
  unsigned b = g / HW, hw = g % HW;                                      \
  const float* xb = x + (size_t)b * CIN * HW + hw;                       \
  float4 a0 = make_float4(cls_b[0], cls_b[1], cls_b[2], cls_b[3]);       \
  float4 a1 = make_float4(cls_b[4], cls_b[5], cls_b[6], cls_b[7]);       \
  float4 a2 = make_float4(cls_b[8], cls_b[9], cls_b[10], cls_b[11]);     \
  float4 a3 = make_float4(cls_b[12], cls_b[13], cls_b[14], cls_b[15]);   \
  float4 a4 = make_float4(cls_b[16], cls_b[17], cls_b[18], cls_b[19]);   \
  float4 a5 = make_float4(cls_b[20], cls_b[21], cls_b[22], cls_b[23]);   \
  _Pragma("unroll 8")                                                    \
  for (int c = 0; c < CIN; ++c) {                                        \
    float xv = xb[(size_t)c * HW];                                       \
    const float4* wr = sw4 + c * 6;                                      \
    float4 w0 = wr[0], w1 = wr[1], w2 = wr[2];                           \
    float4 w3 = wr[3], w4 = wr[4], w5 = wr[5];                           \
    FMA_ROW(a0, w0) FMA_ROW(a1, w1) FMA_ROW(a2, w2)                      \
    FMA_ROW(a3, w3) FMA_ROW(a4, w4) FMA_ROW(a5, w5)                      \
  }                                                                      \
  float s0 = sc4(a0), s1 = sc4(a1), s2 = sc4(a2);                        \
  float s3 = sc4(a3), s4 = sc4(a4), s5 = sc4(a5);

// ---------------- K1: scores -> histogram (+optional score store) ----------------
__global__ __launch_bounds__(256, 4) void k1_hist(
    const float* __restrict__ x, const float* __restrict__ cls_w,
    const float* __restrict__ cls_b, unsigned int* __restrict__ hist,
    float* __restrict__ maxsc, int store) {
  STAGE_W();
  HEAD_BODY();
  unsigned hb = b * NBIN;
  atomicAdd(&hist[hb + (__float_as_uint(s0) >> HSHIFT)], 1u);
  atomicAdd(&hist[hb + (__float_as_uint(s1) >> HSHIFT)], 1u);
  atomicAdd(&hist[hb + (__float_as_uint(s2) >> HSHIFT)], 1u);
  atomicAdd(&hist[hb + (__float_as_uint(s3) >> HSHIFT)], 1u);
  atomicAdd(&hist[hb + (__float_as_uint(s4) >> HSHIFT)], 1u);
  atomicAdd(&hist[hb + (__float_as_uint(s5) >> HSHIFT)], 1u);
  if (store) {
    float* mp = maxsc + (size_t)b * NANCH + hw * 6u;
    mp[0] = s0; mp[1] = s1; mp[2] = s2; mp[3] = s3; mp[4] = s4; mp[5] = s5;
  }
}

// ---------------- K2: threshold bin per batch ----------------
__global__ __launch_bounds__(256) void k2_thresh(
    const unsigned int* __restrict__ hist, unsigned int* __restrict__ thresh) {
  int b = blockIdx.x, tid = threadIdx.x;
  const unsigned* h = hist + (size_t)b * NBIN;
  unsigned r[64];
  unsigned base = tid * 64u;
  unsigned s = 0;
#pragma unroll
  for (int i = 0; i < 64; ++i) { r[i] = h[base + i]; s += r[i]; }
  __shared__ unsigned seg[256];
  seg[tid] = s;
  __syncthreads();
  for (int d = 1; d < 256; d <<= 1) {
    unsigned add = (tid + d < 256) ? seg[tid + d] : 0u;
    __syncthreads();
    seg[tid] += add;
    __syncthreads();
  }
  unsigned above = (tid < 255) ? seg[tid + 1] : 0u;
  if (above < TOPK && above + s >= TOPK) {
    unsigned c = above, T = 0;
    for (int i = 63; i >= 0; --i) {
      c += r[i];
      if (c >= TOPK) { T = base + (unsigned)i; break; }
    }
    thresh[b] = (T > 0) ? T - 1 : 0;   // 1-bin insurance margin
  }
}

// ---------------- K3a: compact from stored scores ----------------
__global__ __launch_bounds__(256) void k3_scores(
    const float* __restrict__ maxsc, const unsigned int* __restrict__ thresh,
    unsigned int* __restrict__ cand_count, unsigned long long* __restrict__ cand) {
  unsigned p = blockIdx.x * 256u + threadIdx.x;   // [0, B*NANCH)
  unsigned b = p / NANCH, n = p % NANCH;
  unsigned bits = __float_as_uint(maxsc[p]);
  if ((bits >> HSHIFT) >= thresh[b]) {
    unsigned pos = atomicAdd(&cand_count[b], 1u);
    if (pos < CAP)
      cand[(size_t)b * CAP + pos] =
          ((unsigned long long)bits << 32) | (unsigned)(~n);
  }
}

// ---------------- K3b: recompute scores, compact ----------------
__global__ __launch_bounds__(256, 4) void k3_recompute(
    const float* __restrict__ x, const float* __restrict__ cls_w,
    const float* __restrict__ cls_b, const unsigned int* __restrict__ thresh,
    unsigned int* __restrict__ cand_count, unsigned long long* __restrict__ cand) {
  STAGE_W();
  HEAD_BODY();
  unsigned T = thresh[b];
  unsigned nb = hw * 6u;
  unsigned bits;
#define PUSH(S, A)                                                       \
  bits = __float_as_uint(S);                                             \
  if ((bits >> HSHIFT) >= T) {                                           \
    unsigned pos = atomicAdd(&cand_count[b], 1u);                        \
    if (pos < CAP)                                                       \
      cand[(size_t)b * CAP + pos] =                                      \
          ((unsigned long long)bits << 32) | (unsigned)(~(nb + A));      \
  }
  PUSH(s0, 0) PUSH(s1, 1) PUSH(s2, 2) PUSH(s3, 3) PUSH(s4, 4) PUSH(s5, 5)
#undef PUSH
}

// ---------------- K4: bitonic sort candidates, emit topk ----------------
__global__ __launch_bounds__(256) void k4_sort(
    const unsigned long long* __restrict__ cand,
    const unsigned int* __restrict__ cand_count, unsigned int* __restrict__ topk) {
  int b = blockIdx.x, tid = threadIdx.x;
  __shared__ unsigned long long sh[SMAX];
  unsigned cnt = cand_count[b];
  if (cnt > CAP) cnt = CAP;
  unsigned S = 128;
  while (S < cnt) S <<= 1;
  for (unsigned t = tid; t < S; t += 256)
    sh[t] = (t < cnt) ? cand[(size_t)b * CAP + t] : 0ULL;
  __syncthreads();
  for (unsigned kk = 2; kk <= S; kk <<= 1) {
    for (unsigned jj = kk >> 1; jj > 0; jj >>= 1) {
      for (unsigned t = tid; t < S; t += 256) {
        unsigned ixj = t ^ jj;
        if (ixj > t) {
          unsigned long long a = sh[t], c = sh[ixj];
          bool sw = ((t & kk) == 0) ? (a < c) : (a > c);  // descending
          if (sw) { sh[t] = c; sh[ixj] = a; }
        }
      }
      __syncthreads();
    }
  }
  if (tid < TOPK)
    topk[b * TOPK + tid] = ~(unsigned)(sh[tid] & 0xFFFFFFFFULL);
}

// ---------------- K5: final heads + decode for selected anchors ----------------
__global__ __launch_bounds__(256) void k5_out(
    const float* __restrict__ x, const float* __restrict__ cls_w,
    const float* __restrict__ cls_b, const float* __restrict__ reg_w,
    const float* __restrict__ reg_b, const float* __restrict__ anchors,
    const unsigned int* __restrict__ topk, float* __restrict__ out) {
  int bk = blockIdx.x;            // [0, B*TOPK)
  int b = bk / TOPK, k = bk % TOPK;
  unsigned n = topk[b * TOPK + k];
  int a = (int)(n % AA);
  unsigned hw = n / AA;
  int tid = threadIdx.x;          // 256 == CIN

  float xv = x[(size_t)b * CIN * HW + (size_t)tid * HW + hw];
  float part[11];
#pragma unroll
  for (int j = 0; j < 4; ++j) part[j] = xv * cls_w[(a * 4 + j) * CIN + tid];
#pragma unroll
  for (int j = 0; j < 7; ++j) part[4 + j] = xv * reg_w[(a * 7 + j) * CIN + tid];

#pragma unroll
  for (int j = 0; j < 11; ++j) {
    float v = part[j];
    for (int off = 32; off > 0; off >>= 1) v += __shfl_down(v, off, 64);
    part[j] = v;
  }
  __shared__ float red[4][11];
  int wave = tid >> 6, lane = tid & 63;
  if (lane == 0) {
#pragma unroll
    for (int j = 0; j < 11; ++j) red[wave][j] = part[j];
  }
  __syncthreads();
  if (tid == 0) {
    float tot[11];
#pragma unroll
    for (int j = 0; j < 11; ++j)
      tot[j] = red[0][j] + red[1][j] + red[2][j] + red[3][j];
    float l0 = tot[0] + cls_b[a * 4 + 0];
    float l1 = tot[1] + cls_b[a * 4 + 1];
    float l2 = tot[2] + cls_b[a * 4 + 2];
    float l3 = tot[3] + cls_b[a * 4 + 3];
    float m = fmaxf(fmaxf(l0, l1), fmaxf(l2, l3));
    float e0 = expf(l0 - m), e1 = expf(l1 - m);
    float e2 = expf(l2 - m), e3 = expf(l3 - m);
    float inv = 1.0f / (e0 + e1 + e2 + e3);
    float* os = out + ((size_t)b * TOPK + k) * 4;
    os[0] = e0 * inv; os[1] = e1 * inv; os[2] = e2 * inv; os[3] = e3 * inv;
    const float* an = anchors + (size_t)n * 7;
    float xa = an[0], ya = an[1], za = an[2];
    float dxa = an[3], dya = an[4], dza = an[5], ra = an[6];
    float xt = tot[4] + reg_b[a * 7 + 0];
    float yt = tot[5] + reg_b[a * 7 + 1];
    float zt = tot[6] + reg_b[a * 7 + 2];
    float dxt = tot[7] + reg_b[a * 7 + 3];
    float dyt = tot[8] + reg_b[a * 7 + 4];
    float dzt = tot[9] + reg_b[a * 7 + 5];
    float rt = tot[10] + reg_b[a * 7 + 6];
    float diag = sqrtf(dxa * dxa + dya * dya);
    float* ob = out + (size_t)BB * TOPK * 4 + ((size_t)b * TOPK + k) * 7;
    ob[0] = xt * diag + xa;
    ob[1] = yt * diag + ya;
    ob[2] = zt * dza + za;
    ob[3] = expf(dxt) * dxa;
    ob[4] = expf(dyt) * dya;
    ob[5] = expf(dzt) * dza;
    ob[6] = rt + ra;
  }
}

extern "C" void kernel_launch(void* const* d_in, const int* in_sizes, int n_in,
                              void* d_out, int out_size, void* d_ws, size_t ws_size,
                              hipStream_t stream) {
  const float* x       = (const float*)d_in[0];
  const float* cls_w   = (const float*)d_in[1];
  const float* cls_b   = (const float*)d_in[2];
  const float* reg_w   = (const float*)d_in[3];
  const float* reg_b   = (const float*)d_in[4];
  const float* anchors = (const float*)d_in[5];
  float* out = (float*)d_out;

  // workspace layout
  char* ws = (char*)d_ws;
  size_t off = 0;
  unsigned int* hist = (unsigned int*)(ws + off);        off += (size_t)BB * NBIN * 4;   // 256 KB
  unsigned int* cand_count = (unsigned int*)(ws + off);  off += 64;
  unsigned int* thresh = (unsigned int*)(ws + off);      off += 64;
  unsigned long long* cand = (unsigned long long*)(ws + off); off += (size_t)BB * CAP * 8; // 256 KB
  unsigned int* topk = (unsigned int*)(ws + off);        off += ((size_t)BB * TOPK * 4 + 63) & ~(size_t)63;
  float* maxsc = (float*)(ws + off);
  size_t scores_bytes = (size_t)BB * NANCH * 4;          // 3.4 MB
  const int store = (ws_size >= off + scores_bytes) ? 1 : 0;

  hipMemsetAsync(hist, 0, (size_t)BB * NBIN * 4 + 64, stream);

  const int GRID1 = (BB * HW) / 256;      // 550
  k1_hist<<<GRID1, 256, 0, stream>>>(x, cls_w, cls_b, hist, maxsc, store);
  k2_thresh<<<BB, 256, 0, stream>>>(hist, thresh);
  if (store) {
    k3_scores<<<(BB * NANCH) / 256, 256, 0, stream>>>(maxsc, thresh, cand_count, cand);
  } else {
    k3_recompute<<<GRID1, 256, 0, stream>>>(x, cls_w, cls_b, thresh, cand_count, cand);
  }
  k4_sort<<<BB, 256, 0, stream>>>(cand, cand_count, topk);
  k5_out<<<BB * TOPK, 256, 0, stream>>>(x, cls_w, cls_b, reg_w, reg_b, anchors,
                                        topk, out);
}

// Round 4
// 372.530 us; speedup vs baseline: 1.6885x; 1.3546x over previous
//
#include <hip/hip_runtime.h>

#define BB 4
#define CIN 256
#define HW 35200            // 200*176
#define AA 6
#define NANCH (AA * HW)     // 211200
#define TOPK 100
#define HSHIFT 17           // bin = float_bits >> 17 (monotone for s>=0)
#define NBIN 16384
#define CAP 8192            // candidates per batch
#define SMAX 8192           // bitonic sort max size (64KB LDS)
#define TILES 138           // ceil(HW/256)

__device__ __forceinline__ float sc4(float4 l) {
  float m = fmaxf(fmaxf(l.x, l.y), fmaxf(l.z, l.w));
  float e0 = expf(l.x - m), e1 = expf(l.y - m);
  float e2 = expf(l.z - m), e3 = expf(l.w - m);
  return fmaxf(fmaxf(e1, e2), e3) / (e0 + e1 + e2 + e3);
}

#define F4Z make_float4(0.f, 0.f, 0.f, 0.f)
#define DEF_ACC(P)                                         \
  float4 A##P##0 = F4Z, A##P##1 = F4Z, A##P##2 = F4Z,      \
         A##P##3 = F4Z, A##P##4 = F4Z, A##P##5 = F4Z;
#define FMA4(A, W, S)                                      \
  A.x = fmaf(S, W.x, A.x); A.y = fmaf(S, W.y, A.y);        \
  A.z = fmaf(S, W.z, A.z); A.w = fmaf(S, W.w, A.w);
#define FMA_P(P, S)                                        \
  FMA4(A##P##0, w0, S) FMA4(A##P##1, w1, S)                \
  FMA4(A##P##2, w2, S) FMA4(A##P##3, w3, S)                \
  FMA4(A##P##4, w4, S) FMA4(A##P##5, w5, S)

// MODE 0: hist + store scores; MODE 1: hist only; MODE 2: compact candidates
template <int MODE>
__global__ __launch_bounds__(256, 2) void k1_head(
    const float* __restrict__ x, const float* __restrict__ cls_w,
    const float* __restrict__ cls_b, unsigned int* __restrict__ hist, int nsh,
    float* __restrict__ maxsc, const unsigned int* __restrict__ thresh,
    unsigned int* __restrict__ cand_count, unsigned long long* __restrict__ cand) {
  unsigned bid = blockIdx.x;
  unsigned b = bid / TILES, tile = bid % TILES;
  int tid = threadIdx.x, wave = tid >> 6, lane = tid & 63;

  __shared__ __align__(16) float swf[CIN * 24];        // 24 KB, [c][o]
  __shared__ __align__(16) float4 red4[6 * 256];       // 24 KB, [og][pos]
  for (int i = tid; i < CIN * 24; i += 256) {
    int o = i / CIN, c = i % CIN;
    swf[c * 24 + o] = cls_w[i];
  }
  __syncthreads();
  const float4* sw4 = (const float4*)swf;

  int hw0 = tile * 256 + lane * 4;
  int hwc = (hw0 <= HW - 4) ? hw0 : (HW - 4);          // clamp tail tile
  const float* xb = x + (size_t)b * CIN * HW + (size_t)(wave * 64) * HW + hwc;

  DEF_ACC(0) DEF_ACC(1) DEF_ACC(2) DEF_ACC(3)

#pragma unroll 8
  for (int cc = 0; cc < 64; ++cc) {
    float4 xv = *(const float4*)(xb + (size_t)cc * HW);
    const float4* wr = sw4 + (wave * 64 + cc) * 6;
    float4 w0 = wr[0], w1 = wr[1], w2 = wr[2];
    float4 w3 = wr[3], w4 = wr[4], w5 = wr[5];
    FMA_P(0, xv.x) FMA_P(1, xv.y) FMA_P(2, xv.z) FMA_P(3, xv.w)
  }

  // deterministic cross-wave reduction: wave0 stores, waves 1..3 add in order
  int base = lane * 4;
#define RED1(OG, P, A)                                                      \
  { int idx = OG * 256 + base + P;                                          \
    if (w == 0) red4[idx] = A;                                              \
    else { float4 t = red4[idx]; t.x += A.x; t.y += A.y; t.z += A.z;        \
           t.w += A.w; red4[idx] = t; } }
#define REDP(P)                                                             \
  RED1(0, P, A##P##0) RED1(1, P, A##P##1) RED1(2, P, A##P##2)               \
  RED1(3, P, A##P##3) RED1(4, P, A##P##4) RED1(5, P, A##P##5)
  for (int w = 0; w < 4; ++w) {
    if (wave == w) { REDP(0) REDP(1) REDP(2) REDP(3) }
    __syncthreads();
  }
#undef REDP
#undef RED1

  // final: one position per thread
  int pos = tid;
  int hwg = (int)tile * 256 + pos;
  if (hwg < HW) {
    float4 r0 = red4[0 * 256 + pos], r1 = red4[1 * 256 + pos];
    float4 r2 = red4[2 * 256 + pos], r3 = red4[3 * 256 + pos];
    float4 r4 = red4[4 * 256 + pos], r5 = red4[5 * 256 + pos];
#define ADDB(R, A)                                          \
    R.x += cls_b[4 * A + 0]; R.y += cls_b[4 * A + 1];       \
    R.z += cls_b[4 * A + 2]; R.w += cls_b[4 * A + 3];
    ADDB(r0, 0) ADDB(r1, 1) ADDB(r2, 2) ADDB(r3, 3) ADDB(r4, 4) ADDB(r5, 5)
#undef ADDB
    float s0 = sc4(r0), s1 = sc4(r1), s2 = sc4(r2);
    float s3 = sc4(r3), s4 = sc4(r4), s5 = sc4(r5);
    unsigned u0 = __float_as_uint(s0), u1 = __float_as_uint(s1);
    unsigned u2 = __float_as_uint(s2), u3 = __float_as_uint(s3);
    unsigned u4 = __float_as_uint(s4), u5 = __float_as_uint(s5);
    if (MODE <= 1) {
      unsigned hb = (b * (unsigned)nsh + (bid & (unsigned)(nsh - 1))) * NBIN;
      atomicAdd(&hist[hb + (u0 >> HSHIFT)], 1u);
      atomicAdd(&hist[hb + (u1 >> HSHIFT)], 1u);
      atomicAdd(&hist[hb + (u2 >> HSHIFT)], 1u);
      atomicAdd(&hist[hb + (u3 >> HSHIFT)], 1u);
      atomicAdd(&hist[hb + (u4 >> HSHIFT)], 1u);
      atomicAdd(&hist[hb + (u5 >> HSHIFT)], 1u);
      if (MODE == 0) {
        float* mp = maxsc + (size_t)b * NANCH + (size_t)hwg * 6u;
        mp[0] = s0; mp[1] = s1; mp[2] = s2; mp[3] = s3; mp[4] = s4; mp[5] = s5;
      }
    } else {
      unsigned T = thresh[b];
      unsigned nb = (unsigned)hwg * 6u;
#define PUSH(U, A)                                                          \
      if (((U) >> HSHIFT) >= T) {                                           \
        unsigned posi = atomicAdd(&cand_count[b], 1u);                      \
        if (posi < CAP)                                                     \
          cand[(size_t)b * CAP + posi] =                                    \
              ((unsigned long long)(U) << 32) | (unsigned)(~(nb + A));      \
      }
      PUSH(u0, 0) PUSH(u1, 1) PUSH(u2, 2) PUSH(u3, 3) PUSH(u4, 4) PUSH(u5, 5)
#undef PUSH
    }
  }
}

// ---------------- K2: threshold bin per batch ----------------
__global__ __launch_bounds__(256) void k2_thresh(
    const unsigned int* __restrict__ hist, int nsh,
    unsigned int* __restrict__ thresh) {
  int b = blockIdx.x, tid = threadIdx.x;
  unsigned r[64];
  unsigned base = tid * 64u;
  unsigned s = 0;
#pragma unroll
  for (int i = 0; i < 64; ++i) r[i] = 0;
  for (int sh = 0; sh < nsh; ++sh) {
    const unsigned* h = hist + ((size_t)b * nsh + sh) * NBIN;
#pragma unroll
    for (int i = 0; i < 64; ++i) r[i] += h[base + i];
  }
#pragma unroll
  for (int i = 0; i < 64; ++i) s += r[i];
  __shared__ unsigned seg[256];
  seg[tid] = s;
  __syncthreads();
  for (int d = 1; d < 256; d <<= 1) {
    unsigned add = (tid + d < 256) ? seg[tid + d] : 0u;
    __syncthreads();
    seg[tid] += add;
    __syncthreads();
  }
  unsigned above = (tid < 255) ? seg[tid + 1] : 0u;
  if (above < TOPK && above + s >= TOPK) {
    unsigned c = above, T = 0;
    for (int i = 63; i >= 0; --i) {
      c += r[i];
      if (c >= TOPK) { T = base + (unsigned)i; break; }
    }
    thresh[b] = (T > 0) ? T - 1 : 0;   // 1-bin insurance margin
  }
}

// ---------------- K3a: compact from stored scores ----------------
__global__ __launch_bounds__(256) void k3_scores(
    const float* __restrict__ maxsc, const unsigned int* __restrict__ thresh,
    unsigned int* __restrict__ cand_count, unsigned long long* __restrict__ cand) {
  unsigned p = blockIdx.x * 256u + threadIdx.x;   // [0, B*NANCH)
  unsigned b = p / NANCH, n = p % NANCH;
  unsigned bits = __float_as_uint(maxsc[p]);
  if ((bits >> HSHIFT) >= thresh[b]) {
    unsigned pos = atomicAdd(&cand_count[b], 1u);
    if (pos < CAP)
      cand[(size_t)b * CAP + pos] =
          ((unsigned long long)bits << 32) | (unsigned)(~n);
  }
}

// ---------------- K4: bitonic sort candidates, emit topk ----------------
__global__ __launch_bounds__(256) void k4_sort(
    const unsigned long long* __restrict__ cand,
    const unsigned int* __restrict__ cand_count, unsigned int* __restrict__ topk) {
  int b = blockIdx.x, tid = threadIdx.x;
  __shared__ unsigned long long sh[SMAX];
  unsigned cnt = cand_count[b];
  if (cnt > CAP) cnt = CAP;
  unsigned S = 128;
  while (S < cnt) S <<= 1;
  for (unsigned t = tid; t < S; t += 256)
    sh[t] = (t < cnt) ? cand[(size_t)b * CAP + t] : 0ULL;
  __syncthreads();
  for (unsigned kk = 2; kk <= S; kk <<= 1) {
    for (unsigned jj = kk >> 1; jj > 0; jj >>= 1) {
      for (unsigned t = tid; t < S; t += 256) {
        unsigned ixj = t ^ jj;
        if (ixj > t) {
          unsigned long long a = sh[t], c = sh[ixj];
          bool sw = ((t & kk) == 0) ? (a < c) : (a > c);  // descending
          if (sw) { sh[t] = c; sh[ixj] = a; }
        }
      }
      __syncthreads();
    }
  }
  if (tid < TOPK)
    topk[b * TOPK + tid] = ~(unsigned)(sh[tid] & 0xFFFFFFFFULL);
}

// ---------------- K5: final heads + decode for selected anchors ----------------
__global__ __launch_bounds__(256) void k5_out(
    const float* __restrict__ x, const float* __restrict__ cls_w,
    const float* __restrict__ cls_b, const float* __restrict__ reg_w,
    const float* __restrict__ reg_b, const float* __restrict__ anchors,
    const unsigned int* __restrict__ topk, float* __restrict__ out) {
  int bk = blockIdx.x;            // [0, B*TOPK)
  int b = bk / TOPK, k = bk % TOPK;
  unsigned n = topk[b * TOPK + k];
  int a = (int)(n % AA);
  unsigned hw = n / AA;
  int tid = threadIdx.x;          // 256 == CIN

  float xv = x[(size_t)b * CIN * HW + (size_t)tid * HW + hw];
  float part[11];
#pragma unroll
  for (int j = 0; j < 4; ++j) part[j] = xv * cls_w[(a * 4 + j) * CIN + tid];
#pragma unroll
  for (int j = 0; j < 7; ++j) part[4 + j] = xv * reg_w[(a * 7 + j) * CIN + tid];

#pragma unroll
  for (int j = 0; j < 11; ++j) {
    float v = part[j];
    for (int off = 32; off > 0; off >>= 1) v += __shfl_down(v, off, 64);
    part[j] = v;
  }
  __shared__ float red[4][11];
  int wave = tid >> 6, lane = tid & 63;
  if (lane == 0) {
#pragma unroll
    for (int j = 0; j < 11; ++j) red[wave][j] = part[j];
  }
  __syncthreads();
  if (tid == 0) {
    float tot[11];
#pragma unroll
    for (int j = 0; j < 11; ++j)
      tot[j] = red[0][j] + red[1][j] + red[2][j] + red[3][j];
    float l0 = tot[0] + cls_b[a * 4 + 0];
    float l1 = tot[1] + cls_b[a * 4 + 1];
    float l2 = tot[2] + cls_b[a * 4 + 2];
    float l3 = tot[3] + cls_b[a * 4 + 3];
    float m = fmaxf(fmaxf(l0, l1), fmaxf(l2, l3));
    float e0 = expf(l0 - m), e1 = expf(l1 - m);
    float e2 = expf(l2 - m), e3 = expf(l3 - m);
    float inv = 1.0f / (e0 + e1 + e2 + e3);
    float* os = out + ((size_t)b * TOPK + k) * 4;
    os[0] = e0 * inv; os[1] = e1 * inv; os[2] = e2 * inv; os[3] = e3 * inv;
    const float* an = anchors + (size_t)n * 7;
    float xa = an[0], ya = an[1], za = an[2];
    float dxa = an[3], dya = an[4], dza = an[5], ra = an[6];
    float xt = tot[4] + reg_b[a * 7 + 0];
    float yt = tot[5] + reg_b[a * 7 + 1];
    float zt = tot[6] + reg_b[a * 7 + 2];
    float dxt = tot[7] + reg_b[a * 7 + 3];
    float dyt = tot[8] + reg_b[a * 7 + 4];
    float dzt = tot[9] + reg_b[a * 7 + 5];
    float rt = tot[10] + reg_b[a * 7 + 6];
    float diag = sqrtf(dxa * dxa + dya * dya);
    float* ob = out + (size_t)BB * TOPK * 4 + ((size_t)b * TOPK + k) * 7;
    ob[0] = xt * diag + xa;
    ob[1] = yt * diag + ya;
    ob[2] = zt * dza + za;
    ob[3] = expf(dxt) * dxa;
    ob[4] = expf(dyt) * dya;
    ob[5] = expf(dzt) * dza;
    ob[6] = rt + ra;
  }
}

extern "C" void kernel_launch(void* const* d_in, const int* in_sizes, int n_in,
                              void* d_out, int out_size, void* d_ws, size_t ws_size,
                              hipStream_t stream) {
  const float* x       = (const float*)d_in[0];
  const float* cls_w   = (const float*)d_in[1];
  const float* cls_b   = (const float*)d_in[2];
  const float* reg_w   = (const float*)d_in[3];
  const float* reg_b   = (const float*)d_in[4];
  const float* anchors = (const float*)d_in[5];
  float* out = (float*)d_out;

  const size_t fixed = 64 + 64 + (size_t)BB * CAP * 8 + 2048;  // counters+thresh+cand+topk
  const size_t scores_bytes = (size_t)BB * NANCH * 4;          // 3.4 MB
  int nsh, store;
  if (ws_size >= (size_t)BB * 4 * NBIN * 4 + fixed + scores_bytes) {
    nsh = 4; store = 1;              // 4-shard hist + stored scores (~4.7 MB)
  } else if (ws_size >= (size_t)BB * 1 * NBIN * 4 + fixed + scores_bytes) {
    nsh = 1; store = 1;
  } else {
    nsh = 1; store = 0;              // minimal: recompute path (~0.8 MB)
  }
  size_t histsz = (size_t)BB * nsh * NBIN * 4;

  char* ws = (char*)d_ws;
  size_t off = 0;
  unsigned int* hist = (unsigned int*)(ws + off);        off += histsz;
  unsigned int* cand_count = (unsigned int*)(ws + off);  off += 64;
  unsigned int* thresh = (unsigned int*)(ws + off);      off += 64;
  unsigned long long* cand = (unsigned long long*)(ws + off); off += (size_t)BB * CAP * 8;
  unsigned int* topk = (unsigned int*)(ws + off);        off += 2048;
  float* maxsc = (float*)(ws + off);

  hipMemsetAsync(hist, 0, histsz + 64, stream);   // hist + cand_count

  const int GRID1 = BB * TILES;   // 552
  if (store) {
    k1_head<0><<<GRID1, 256, 0, stream>>>(x, cls_w, cls_b, hist, nsh, maxsc,
                                          nullptr, nullptr, nullptr);
  } else {
    k1_head<1><<<GRID1, 256, 0, stream>>>(x, cls_w, cls_b, hist, nsh, nullptr,
                                          nullptr, nullptr, nullptr);
  }
  k2_thresh<<<BB, 256, 0, stream>>>(hist, nsh, thresh);
  if (store) {
    k3_scores<<<(BB * NANCH) / 256, 256, 0, stream>>>(maxsc, thresh, cand_count, cand);
  } else {
    k1_head<2><<<GRID1, 256, 0, stream>>>(x, cls_w, cls_b, hist, nsh, nullptr,
                                          thresh, cand_count, cand);
  }
  k4_sort<<<BB, 256, 0, stream>>>(cand, cand_count, topk);
  k5_out<<<BB * TOPK, 256, 0, stream>>>(x, cls_w, cls_b, reg_w, reg_b, anchors,
                                        topk, out);
}

// Round 5
// 277.931 us; speedup vs baseline: 2.2632x; 1.3404x over previous
//
#include <hip/hip_runtime.h>

#define BB 4
#define CIN 256
#define HW 35200            // 200*176
#define AA 6
#define NANCH (AA * HW)     // 211200
#define TOPK 100
#define NBIN 4096           // mapped score bins
#define BINBASE 28416       // 0x37800000 >> 15  (s = 2^-16 .. 1.0 range)
#define CAP 4096            // candidates per batch
#define SMAX 4096           // bitonic sort max size
#define TILES 138           // ceil(HW/256)

// monotone (clamped) bin map for score bits, s in [0,1]
__device__ __forceinline__ unsigned sbin(unsigned bits) {
  int v = (int)(bits >> 15) - BINBASE;
  v = v < 0 ? 0 : v;
  v = v > (NBIN - 1) ? (NBIN - 1) : v;
  return (unsigned)v;
}

__device__ __forceinline__ float sc4(float4 l) {
  float m = fmaxf(fmaxf(l.x, l.y), fmaxf(l.z, l.w));
  float e0 = expf(l.x - m), e1 = expf(l.y - m);
  float e2 = expf(l.z - m), e3 = expf(l.w - m);
  return fmaxf(fmaxf(e1, e2), e3) / (e0 + e1 + e2 + e3);
}

#define FMA4(A, W, S)                                      \
  A.x = fmaf(S, W.x, A.x); A.y = fmaf(S, W.y, A.y);        \
  A.z = fmaf(S, W.z, A.z); A.w = fmaf(S, W.w, A.w);

// ---------------- K1: cls head -> scores + LDS histogram ----------------
__global__ __launch_bounds__(256, 4) void k1_scores(
    const float* __restrict__ x, const float* __restrict__ cls_w,
    const float* __restrict__ cls_b, unsigned int* __restrict__ hist,
    float* __restrict__ maxsc) {
  int bid = blockIdx.x;
  int b = bid / TILES, tile = bid % TILES;
  int tid = threadIdx.x;

  __shared__ __align__(16) float swf[CIN * 24];   // 24 KB, [c][o] transposed
  __shared__ unsigned lh[NBIN];                   // 16 KB block-local histogram
  for (int i = tid; i < CIN * 24; i += 256)
    swf[(i % CIN) * 24 + (i / CIN)] = cls_w[i];   // coalesced global read
  for (int i = tid; i < NBIN; i += 256) lh[i] = 0;
  __syncthreads();
  const float4* sw4 = (const float4*)swf;

  int hwg = tile * 256 + tid;
  bool act = hwg < HW;
  int hwc = act ? hwg : (HW - 1);
  const float* xb = x + (size_t)b * CIN * HW + hwc;

  float4 a0 = make_float4(cls_b[0], cls_b[1], cls_b[2], cls_b[3]);
  float4 a1 = make_float4(cls_b[4], cls_b[5], cls_b[6], cls_b[7]);
  float4 a2 = make_float4(cls_b[8], cls_b[9], cls_b[10], cls_b[11]);
  float4 a3 = make_float4(cls_b[12], cls_b[13], cls_b[14], cls_b[15]);
  float4 a4 = make_float4(cls_b[16], cls_b[17], cls_b[18], cls_b[19]);
  float4 a5 = make_float4(cls_b[20], cls_b[21], cls_b[22], cls_b[23]);

#pragma unroll 8
  for (int c = 0; c < CIN; ++c) {
    float xv = xb[(size_t)c * HW];
    const float4* wr = sw4 + c * 6;
    float4 w0 = wr[0], w1 = wr[1], w2 = wr[2];
    float4 w3 = wr[3], w4 = wr[4], w5 = wr[5];
    FMA4(a0, w0, xv) FMA4(a1, w1, xv) FMA4(a2, w2, xv)
    FMA4(a3, w3, xv) FMA4(a4, w4, xv) FMA4(a5, w5, xv)
  }

  if (act) {
    float s0 = sc4(a0), s1 = sc4(a1), s2 = sc4(a2);
    float s3 = sc4(a3), s4 = sc4(a4), s5 = sc4(a5);
    float* mp = maxsc + (size_t)b * NANCH + (size_t)hwg * 6u;
    mp[0] = s0; mp[1] = s1; mp[2] = s2; mp[3] = s3; mp[4] = s4; mp[5] = s5;
    atomicAdd(&lh[sbin(__float_as_uint(s0))], 1u);
    atomicAdd(&lh[sbin(__float_as_uint(s1))], 1u);
    atomicAdd(&lh[sbin(__float_as_uint(s2))], 1u);
    atomicAdd(&lh[sbin(__float_as_uint(s3))], 1u);
    atomicAdd(&lh[sbin(__float_as_uint(s4))], 1u);
    atomicAdd(&lh[sbin(__float_as_uint(s5))], 1u);
  }
  __syncthreads();
  unsigned* gh = hist + (size_t)b * NBIN;
  for (int i = tid; i < NBIN; i += 256) {
    unsigned c = lh[i];
    if (c) atomicAdd(&gh[i], c);   // scattered addresses, <=552 adds per bin
  }
}

// ---------------- K2: threshold bin per batch ----------------
__global__ __launch_bounds__(256) void k2_thresh(
    const unsigned int* __restrict__ hist, unsigned int* __restrict__ thresh) {
  int b = blockIdx.x, tid = threadIdx.x;
  const unsigned* h = hist + (size_t)b * NBIN;
  unsigned r[16];
  unsigned s = 0;
#pragma unroll
  for (int i = 0; i < 16; ++i) { r[i] = h[tid * 16 + i]; s += r[i]; }
  __shared__ unsigned seg[256];
  seg[tid] = s;
  __syncthreads();
  for (int d = 1; d < 256; d <<= 1) {   // inclusive suffix scan
    unsigned add = (tid + d < 256) ? seg[tid + d] : 0u;
    __syncthreads();
    seg[tid] += add;
    __syncthreads();
  }
  unsigned above = (tid < 255) ? seg[tid + 1] : 0u;
  if (above < TOPK && above + s >= TOPK) {   // exactly one thread
    unsigned c = above, T = 0;
    for (int i = 15; i >= 0; --i) {
      c += r[i];
      if (c >= TOPK) { T = tid * 16u + (unsigned)i; break; }
    }
    thresh[b] = T;
  }
}

// ---------------- K3: compact candidates (wave-aggregated atomics) ----------------
__global__ __launch_bounds__(256) void k3_compact(
    const float* __restrict__ maxsc, const unsigned int* __restrict__ thresh,
    unsigned int* __restrict__ cand_count, unsigned long long* __restrict__ cand) {
  unsigned p = blockIdx.x * 256u + threadIdx.x;   // [0, B*NANCH)
  unsigned b = p / NANCH, n = p % NANCH;          // b block-uniform (NANCH%256==0)
  unsigned bits = __float_as_uint(maxsc[p]);
  bool pred = sbin(bits) >= thresh[b];
  unsigned long long mask = __ballot(pred);
  if (mask) {
    int lane = threadIdx.x & 63;
    int leader = (int)__ffsll((unsigned long long)mask) - 1;
    unsigned base = 0;
    if (lane == leader)
      base = atomicAdd(&cand_count[b], (unsigned)__popcll(mask));
    base = __shfl(base, leader, 64);
    if (pred) {
      unsigned pos = base + (unsigned)__popcll(mask & ((1ull << lane) - 1ull));
      if (pos < CAP)
        cand[(size_t)b * CAP + pos] =
            ((unsigned long long)bits << 32) | (unsigned)(~n);
    }
  }
}

// ---------------- K4: bitonic sort candidates, emit topk ----------------
__global__ __launch_bounds__(256) void k4_sort(
    const unsigned long long* __restrict__ cand,
    const unsigned int* __restrict__ cand_count, unsigned int* __restrict__ topk) {
  int b = blockIdx.x, tid = threadIdx.x;
  __shared__ unsigned long long sh[SMAX];
  unsigned cnt = cand_count[b];
  if (cnt > CAP) cnt = CAP;
  unsigned S = 128;
  while (S < cnt) S <<= 1;
  for (unsigned t = tid; t < S; t += 256)
    sh[t] = (t < cnt) ? cand[(size_t)b * CAP + t] : 0ULL;
  __syncthreads();
  for (unsigned kk = 2; kk <= S; kk <<= 1) {
    for (unsigned jj = kk >> 1; jj > 0; jj >>= 1) {
      for (unsigned t = tid; t < S; t += 256) {
        unsigned ixj = t ^ jj;
        if (ixj > t) {
          unsigned long long a = sh[t], c = sh[ixj];
          bool sw = ((t & kk) == 0) ? (a < c) : (a > c);  // descending
          if (sw) { sh[t] = c; sh[ixj] = a; }
        }
      }
      __syncthreads();
    }
  }
  if (tid < TOPK)
    topk[b * TOPK + tid] = ~(unsigned)(sh[tid] & 0xFFFFFFFFULL);
}

// ---------------- K5: final heads + decode for selected anchors ----------------
__global__ __launch_bounds__(256) void k5_out(
    const float* __restrict__ x, const float* __restrict__ cls_w,
    const float* __restrict__ cls_b, const float* __restrict__ reg_w,
    const float* __restrict__ reg_b, const float* __restrict__ anchors,
    const unsigned int* __restrict__ topk, float* __restrict__ out) {
  int bk = blockIdx.x;            // [0, B*TOPK)
  int b = bk / TOPK, k = bk % TOPK;
  unsigned n = topk[b * TOPK + k];
  int a = (int)(n % AA);
  unsigned hw = n / AA;
  int tid = threadIdx.x;          // 256 == CIN

  float xv = x[(size_t)b * CIN * HW + (size_t)tid * HW + hw];
  float part[11];
#pragma unroll
  for (int j = 0; j < 4; ++j) part[j] = xv * cls_w[(a * 4 + j) * CIN + tid];
#pragma unroll
  for (int j = 0; j < 7; ++j) part[4 + j] = xv * reg_w[(a * 7 + j) * CIN + tid];

#pragma unroll
  for (int j = 0; j < 11; ++j) {
    float v = part[j];
    for (int off = 32; off > 0; off >>= 1) v += __shfl_down(v, off, 64);
    part[j] = v;
  }
  __shared__ float red[4][11];
  int wave = tid >> 6, lane = tid & 63;
  if (lane == 0) {
#pragma unroll
    for (int j = 0; j < 11; ++j) red[wave][j] = part[j];
  }
  __syncthreads();
  if (tid == 0) {
    float tot[11];
#pragma unroll
    for (int j = 0; j < 11; ++j)
      tot[j] = red[0][j] + red[1][j] + red[2][j] + red[3][j];
    float l0 = tot[0] + cls_b[a * 4 + 0];
    float l1 = tot[1] + cls_b[a * 4 + 1];
    float l2 = tot[2] + cls_b[a * 4 + 2];
    float l3 = tot[3] + cls_b[a * 4 + 3];
    float m = fmaxf(fmaxf(l0, l1), fmaxf(l2, l3));
    float e0 = expf(l0 - m), e1 = expf(l1 - m);
    float e2 = expf(l2 - m), e3 = expf(l3 - m);
    float inv = 1.0f / (e0 + e1 + e2 + e3);
    float* os = out + ((size_t)b * TOPK + k) * 4;
    os[0] = e0 * inv; os[1] = e1 * inv; os[2] = e2 * inv; os[3] = e3 * inv;
    const float* an = anchors + (size_t)n * 7;
    float xa = an[0], ya = an[1], za = an[2];
    float dxa = an[3], dya = an[4], dza = an[5], ra = an[6];
    float xt = tot[4] + reg_b[a * 7 + 0];
    float yt = tot[5] + reg_b[a * 7 + 1];
    float zt = tot[6] + reg_b[a * 7 + 2];
    float dxt = tot[7] + reg_b[a * 7 + 3];
    float dyt = tot[8] + reg_b[a * 7 + 4];
    float dzt = tot[9] + reg_b[a * 7 + 5];
    float rt = tot[10] + reg_b[a * 7 + 6];
    float diag = sqrtf(dxa * dxa + dya * dya);
    float* ob = out + (size_t)BB * TOPK * 4 + ((size_t)b * TOPK + k) * 7;
    ob[0] = xt * diag + xa;
    ob[1] = yt * diag + ya;
    ob[2] = zt * dza + za;
    ob[3] = expf(dxt) * dxa;
    ob[4] = expf(dyt) * dya;
    ob[5] = expf(dzt) * dza;
    ob[6] = rt + ra;
  }
}

extern "C" void kernel_launch(void* const* d_in, const int* in_sizes, int n_in,
                              void* d_out, int out_size, void* d_ws, size_t ws_size,
                              hipStream_t stream) {
  const float* x       = (const float*)d_in[0];
  const float* cls_w   = (const float*)d_in[1];
  const float* cls_b   = (const float*)d_in[2];
  const float* reg_w   = (const float*)d_in[3];
  const float* reg_b   = (const float*)d_in[4];
  const float* anchors = (const float*)d_in[5];
  float* out = (float*)d_out;

  // workspace layout (~3.6 MB total; r4 proved ws >= 4.7 MB available)
  char* ws = (char*)d_ws;
  size_t off = 0;
  unsigned int* hist = (unsigned int*)(ws + off);        off += (size_t)BB * NBIN * 4; // 64 KB
  unsigned int* cand_count = (unsigned int*)(ws + off);  off += 64;
  unsigned int* thresh = (unsigned int*)(ws + off);      off += 64;
  unsigned long long* cand = (unsigned long long*)(ws + off); off += (size_t)BB * CAP * 8; // 128 KB
  unsigned int* topk = (unsigned int*)(ws + off);        off += 2048;
  float* maxsc = (float*)(ws + off);                     // 3.4 MB

  hipMemsetAsync(hist, 0, (size_t)BB * NBIN * 4 + 64, stream);  // hist + cand_count

  k1_scores<<<BB * TILES, 256, 0, stream>>>(x, cls_w, cls_b, hist, maxsc);
  k2_thresh<<<BB, 256, 0, stream>>>(hist, thresh);
  k3_compact<<<(BB * NANCH) / 256, 256, 0, stream>>>(maxsc, thresh, cand_count, cand);
  k4_sort<<<BB, 256, 0, stream>>>(cand, cand_count, topk);
  k5_out<<<BB * TOPK, 256, 0, stream>>>(x, cls_w, cls_b, reg_w, reg_b, anchors,
                                        topk, out);
}